// Round 5
// baseline (7962.104 us; speedup 1.0000x reference)
//
#include <hip/hip_runtime.h>
#include <math.h>

#define TOK 4096
#define HD 512

typedef _Float16 f16x8 __attribute__((ext_vector_type(8)));
typedef float f32x4 __attribute__((ext_vector_type(4)));

__device__ __forceinline__ float gelu_f(float x) {
    return 0.5f * x * (1.0f + erff(x * 0.70710678118654752f));
}

__device__ __forceinline__ void gload16(const void* g, void* l) {
    __builtin_amdgcn_global_load_lds((const __attribute__((address_space(1))) void*)g,
                                     (__attribute__((address_space(3))) void*)l, 16, 0, 0);
}

__device__ __forceinline__ void split2(float v, _Float16& h, _Float16& l) {
    h = (_Float16)v;
    l = (_Float16)(v - (float)h);
}

// ------------------------------------------------------------------
// fp32 -> (hi,lo) fp16, 8 elems/thread. grid = numel/2048
// ------------------------------------------------------------------
__global__ __launch_bounds__(256)
void split_x_kernel(const float* __restrict__ in, _Float16* __restrict__ hi,
                    _Float16* __restrict__ lo)
{
    const size_t idx = (size_t)blockIdx.x * 256 + threadIdx.x;
    const float4 v0 = *(const float4*)(in + idx * 8);
    const float4 v1 = *(const float4*)(in + idx * 8 + 4);
    float vv[8] = {v0.x, v0.y, v0.z, v0.w, v1.x, v1.y, v1.z, v1.w};
    f16x8 h, l;
    #pragma unroll
    for (int j = 0; j < 8; ++j) {
        _Float16 a, b; split2(vv[j], a, b);
        h[j] = a; l[j] = b;
    }
    *(f16x8*)(hi + idx * 8) = h;
    *(f16x8*)(lo + idx * 8) = l;
}

// ------------------------------------------------------------------
// Weight prep: [Ktot][512] fp32 row-major -> frag layout [Ktot/8][512][8]
// hi/lo fp16 (8 = k-minor). grid = Ktot*512/2048 blocks.
// ------------------------------------------------------------------
__global__ __launch_bounds__(256)
void split_w_kernel(const float* __restrict__ w, _Float16* __restrict__ hi,
                    _Float16* __restrict__ lo)
{
    const int idx = blockIdx.x * 256 + threadIdx.x;
    const int kbG = idx >> 9, n = idx & 511;
    const float* src = w + (((size_t)kbG * 8) << 9) + n;
    f16x8 h, l;
    #pragma unroll
    for (int j = 0; j < 8; ++j) {
        const float v = src[(size_t)j << 9];
        _Float16 a, b; split2(v, a, b);
        h[j] = a; l[j] = b;
    }
    *(f16x8*)(hi + (size_t)idx * 8) = h;
    *(f16x8*)(lo + (size_t)idx * 8) = l;
}

// ------------------------------------------------------------------
// Split-fp16 MFMA GEMM: out[M=4096][512] = act(A[M][K] @ Bfrag + bias)
// ------------------------------------------------------------------
template<int ACT, int OSPLIT>
__global__ __launch_bounds__(256, 2)
void gemm_hh(const _Float16* __restrict__ ah, const _Float16* __restrict__ al,
             const _Float16* __restrict__ bh, const _Float16* __restrict__ bl,
             const float* __restrict__ bias, int K,
             float* __restrict__ outF,
             _Float16* __restrict__ oh, _Float16* __restrict__ ol)
{
    __shared__ _Float16 Ah[2][2048], Al[2][2048];
    const int tid = threadIdx.x;
    const int l = tid & 63, w = tid >> 6;
    const int kb = l >> 4, lr = l & 15;
    const int m0 = blockIdx.y << 6;
    const int wn0 = (blockIdx.x << 7) + (w << 5);
    const int scr = tid & 63, sckb = tid >> 6;
    const int sbase = (tid & 192) * 8;

    f32x4 acc[4][2];
    #pragma unroll
    for (int i = 0; i < 4; ++i)
        #pragma unroll
        for (int j = 0; j < 2; ++j) acc[i][j] = (f32x4){0.f, 0.f, 0.f, 0.f};

    {
        const size_t ga = (size_t)(m0 + scr) * K + sckb * 8;
        gload16(ah + ga, Ah[0] + sbase);
        gload16(al + ga, Al[0] + sbase);
    }
    int cur = 0;
    for (int k0 = 0; k0 < K; k0 += 32) {
        __syncthreads();
        if (k0 + 32 < K) {
            const size_t ga = (size_t)(m0 + scr) * K + k0 + 32 + sckb * 8;
            gload16(ah + ga, Ah[cur ^ 1] + sbase);
            gload16(al + ga, Al[cur ^ 1] + sbase);
        }
        f16x8 fah[4], fal[4];
        #pragma unroll
        for (int i = 0; i < 4; ++i) {
            const int off = (kb * 64 + i * 16 + lr) * 8;
            fah[i] = *(const f16x8*)(Ah[cur] + off);
            fal[i] = *(const f16x8*)(Al[cur] + off);
        }
        #pragma unroll
        for (int j = 0; j < 2; ++j) {
            const size_t gb = ((size_t)(((k0 >> 3) + kb) << 9) + wn0 + j * 16 + lr) * 8;
            const f16x8 fbh = *(const f16x8*)(bh + gb);
            const f16x8 fbl = *(const f16x8*)(bl + gb);
            #pragma unroll
            for (int i = 0; i < 4; ++i) {
                acc[i][j] = __builtin_amdgcn_mfma_f32_16x16x32_f16(fah[i], fbh, acc[i][j], 0, 0, 0);
                acc[i][j] = __builtin_amdgcn_mfma_f32_16x16x32_f16(fah[i], fbl, acc[i][j], 0, 0, 0);
                acc[i][j] = __builtin_amdgcn_mfma_f32_16x16x32_f16(fal[i], fbh, acc[i][j], 0, 0, 0);
            }
        }
        cur ^= 1;
    }
    #pragma unroll
    for (int i = 0; i < 4; ++i)
        #pragma unroll
        for (int j = 0; j < 2; ++j) {
            const int n = wn0 + j * 16 + lr;
            const float bv = bias[n];
            #pragma unroll
            for (int r = 0; r < 4; ++r) {
                const int m = m0 + i * 16 + ((l >> 4) << 2) + r;
                float v = acc[i][j][r] + bv;
                if (ACT) v = gelu_f(v);
                if (OSPLIT) {
                    _Float16 vh, vl; split2(v, vh, vl);
                    oh[((size_t)m << 9) + n] = vh;
                    ol[((size_t)m << 9) + n] = vl;
                } else {
                    outF[((size_t)m << 9) + n] = v;
                }
            }
        }
}

// ------------------------------------------------------------------
// Fused expert, n-slice streaming. One (32-token tile, expert) per block.
// grid = 1024 linear: e = bid&7 (pins expert weights per XCD-L2 via the
// linear round-robin heuristic), tile = bid>>3.
// Per n-slice (64 wide): stage1 H-slice = gelu(X@W1e[:,ns]+b)*rw -> LDS
// (split fp16, 9.2 KB), stage2 acc2 += Hs @ W2e[ns,:] in registers.
// atomicAdd into mixed at the end (bias via init_mixed).
// ------------------------------------------------------------------
__global__ __launch_bounds__(256, 3)
void fused_expert2(const _Float16* __restrict__ xh, const _Float16* __restrict__ xl,
                   const _Float16* __restrict__ w1h, const _Float16* __restrict__ w1l,
                   const _Float16* __restrict__ w2h, const _Float16* __restrict__ w2l,
                   const float* __restrict__ eb1, const float* __restrict__ rw,
                   float* __restrict__ mixed)
{
    __shared__ _Float16 Hh[32][72], Hl[32][72];   // pad 72: 16B-aligned rows
    const int tid = threadIdx.x;
    const int l = tid & 63, w = tid >> 6;
    const int kb = l >> 4, lr = l & 15;
    const int bid = blockIdx.x;
    const int e = bid & 7;
    const int m0 = (bid >> 3) << 5;               // 32-token tile
    const int wm = w & 1, wn = w >> 1;            // 2x2 wave grid

    const _Float16* w1he = w1h + ((size_t)e << 18);
    const _Float16* w1le = w1l + ((size_t)e << 18);
    const _Float16* w2he = w2h + ((size_t)e << 18);
    const _Float16* w2le = w2l + ((size_t)e << 18);

    f32x4 acc2[16];
    #pragma unroll
    for (int j = 0; j < 16; ++j) acc2[j] = (f32x4){0.f, 0.f, 0.f, 0.f};

    const int arow = m0 + wm * 16 + lr;           // stage-1 A row (token)

    for (int ns = 0; ns < 512; ns += 64) {
        // ---- stage 1: acc1 = X @ W1e[:, ns..ns+64) (wave: 16m x 32n) ----
        f32x4 acc1[2];
        acc1[0] = (f32x4){0.f, 0.f, 0.f, 0.f};
        acc1[1] = (f32x4){0.f, 0.f, 0.f, 0.f};
        for (int k0 = 0; k0 < 512; k0 += 32) {
            const size_t ga = ((size_t)arow << 9) + k0 + kb * 8;
            const f16x8 fa_h = *(const f16x8*)(xh + ga);
            const f16x8 fa_l = *(const f16x8*)(xl + ga);
            #pragma unroll
            for (int j = 0; j < 2; ++j) {
                const int n = ns + wn * 32 + j * 16 + lr;
                const size_t gb = ((size_t)(((k0 >> 3) + kb) << 9) + n) * 8;
                const f16x8 fbh = *(const f16x8*)(w1he + gb);
                const f16x8 fbl = *(const f16x8*)(w1le + gb);
                acc1[j] = __builtin_amdgcn_mfma_f32_16x16x32_f16(fa_h, fbh, acc1[j], 0, 0, 0);
                acc1[j] = __builtin_amdgcn_mfma_f32_16x16x32_f16(fa_h, fbl, acc1[j], 0, 0, 0);
                acc1[j] = __builtin_amdgcn_mfma_f32_16x16x32_f16(fa_l, fbh, acc1[j], 0, 0, 0);
            }
        }
        // ---- epilogue 1: gelu + bias + route-scale -> LDS (split fp16) ----
        __syncthreads();   // prev slice's stage-2 reads done
        #pragma unroll
        for (int j = 0; j < 2; ++j) {
            const int n = wn * 32 + j * 16 + lr;
            const float bv = eb1[(e << 9) + ns + n];
            #pragma unroll
            for (int r = 0; r < 4; ++r) {
                const int m = wm * 16 + kb * 4 + r;   // C-layout: row=(l>>4)*4+r
                const float v = gelu_f(acc1[j][r] + bv) * rw[((size_t)(m0 + m) << 3) + e];
                _Float16 vh, vl; split2(v, vh, vl);
                Hh[m][n] = vh; Hl[m][n] = vl;
            }
        }
        __syncthreads();
        // ---- stage 2: acc2 += Hs @ W2e[ns..ns+64, :] (wave: 16m x 256n) ----
        #pragma unroll
        for (int kk = 0; kk < 2; ++kk) {
            const int row = wm * 16 + lr;
            const f16x8 fa_h = *(const f16x8*)(&Hh[row][kk * 32 + kb * 8]);
            const f16x8 fa_l = *(const f16x8*)(&Hl[row][kk * 32 + kb * 8]);
            #pragma unroll
            for (int j = 0; j < 16; ++j) {
                const int n = wn * 256 + j * 16 + lr;
                const size_t gb = ((size_t)((((ns + kk * 32) >> 3) + kb) << 9) + n) * 8;
                const f16x8 fbh = *(const f16x8*)(w2he + gb);
                const f16x8 fbl = *(const f16x8*)(w2le + gb);
                acc2[j] = __builtin_amdgcn_mfma_f32_16x16x32_f16(fa_h, fbh, acc2[j], 0, 0, 0);
                acc2[j] = __builtin_amdgcn_mfma_f32_16x16x32_f16(fa_h, fbl, acc2[j], 0, 0, 0);
                acc2[j] = __builtin_amdgcn_mfma_f32_16x16x32_f16(fa_l, fbh, acc2[j], 0, 0, 0);
            }
        }
    }
    // ---- final: accumulate into mixed ----
    #pragma unroll
    for (int j = 0; j < 16; ++j) {
        const int n = wn * 256 + j * 16 + lr;
        #pragma unroll
        for (int r = 0; r < 4; ++r) {
            const int m = m0 + wm * 16 + kb * 4 + r;
            atomicAdd(&mixed[((size_t)m << 9) + n], acc2[j][r]);
        }
    }
}

// ------------------------------------------------------------------
// mixed init: mixed[m][n] = sum_e rw[m][e] * eb2[e][n]. grid = 2048
// ------------------------------------------------------------------
__global__ __launch_bounds__(256)
void init_mixed(const float* __restrict__ rw, const float* __restrict__ eb2,
                float* __restrict__ mixed)
{
    const int idx = blockIdx.x * 256 + threadIdx.x;
    const int m = idx >> 7, n4 = (idx & 127) << 2;
    float rwv[8];
    #pragma unroll
    for (int e = 0; e < 8; ++e) rwv[e] = rw[(m << 3) + e];
    float4 o = {0.f, 0.f, 0.f, 0.f};
    #pragma unroll
    for (int e = 0; e < 8; ++e) {
        const float4 b = *(const float4*)(eb2 + (e << 9) + n4);
        o.x = fmaf(rwv[e], b.x, o.x); o.y = fmaf(rwv[e], b.y, o.y);
        o.z = fmaf(rwv[e], b.z, o.z); o.w = fmaf(rwv[e], b.w, o.w);
    }
    *(float4*)(mixed + ((size_t)m << 9) + n4) = o;
}

// ------------------------------------------------------------------
// Router softmax
// ------------------------------------------------------------------
__global__ __launch_bounds__(256)
void router_kernel(const float* __restrict__ t,
                   const float* __restrict__ rw2,
                   const float* __restrict__ rb2,
                   float* __restrict__ route_w)
{
    __shared__ float s[512 * 9];
    const int tid = threadIdx.x;
    for (int idx = tid; idx < 4096; idx += 256)
        s[(idx >> 3) * 9 + (idx & 7)] = rw2[idx];
    __syncthreads();
    const int lane = tid & 63;
    const int tok = (blockIdx.x << 2) + (tid >> 6);
    const float* tp = t + ((size_t)tok << 9);
    float acc[8] = {};
    #pragma unroll
    for (int kq = 0; kq < 8; ++kq) {
        const int k = (kq << 6) + lane;
        const float tv = tp[k];
        #pragma unroll
        for (int e = 0; e < 8; ++e)
            acc[e] = fmaf(tv, s[k * 9 + e], acc[e]);
    }
    #pragma unroll
    for (int e = 0; e < 8; ++e)
        #pragma unroll
        for (int off = 32; off; off >>= 1)
            acc[e] += __shfl_xor(acc[e], off, 64);
    float mx = -1e30f;
    #pragma unroll
    for (int e = 0; e < 8; ++e) { acc[e] += rb2[e]; mx = fmaxf(mx, acc[e]); }
    float sum = 0.f;
    #pragma unroll
    for (int e = 0; e < 8; ++e) { acc[e] = expf(acc[e] - mx); sum += acc[e]; }
    const float inv = 1.0f / sum;
    if (lane == 0) {
        #pragma unroll
        for (int e = 0; e < 8; ++e) route_w[(tok << 3) + e] = acc[e] * inv;
    }
}

__global__ __launch_bounds__(256)
void score_kernel(const float* __restrict__ u,
                  const float* __restrict__ sw2,
                  const float* __restrict__ sb2,
                  float* __restrict__ mlog, int mod)
{
    const int tid = threadIdx.x;
    const int lane = tid & 63;
    const int tok = (blockIdx.x << 2) + (tid >> 6);
    const float* up = u + ((size_t)tok << 9);
    float acc = 0.f;
    #pragma unroll
    for (int kq = 0; kq < 8; ++kq) {
        const int k = (kq << 6) + lane;
        acc = fmaf(up[k], sw2[k], acc);
    }
    #pragma unroll
    for (int off = 32; off; off >>= 1) acc += __shfl_xor(acc, off, 64);
    if (lane == 0) mlog[(tok << 2) + mod] = acc + sb2[0];
}

__global__ __launch_bounds__(256)
void final_kernel(const float* __restrict__ mixedb,
                  const float* __restrict__ mlog,
                  const float* __restrict__ g,
                  const float* __restrict__ bta,
                  float* __restrict__ out)
{
    const int tok = blockIdx.x, tid = threadIdx.x;
    float v[4];
    #pragma unroll
    for (int m = 0; m < 4; ++m) v[m] = mlog[(tok << 2) + m];
    int i1 = 0;
    #pragma unroll
    for (int m = 1; m < 4; ++m) if (v[m] > v[i1]) i1 = m;
    int i2 = (i1 == 0) ? 1 : 0;
    for (int m = i2 + 1; m < 4; ++m) if (m != i1 && v[m] > v[i2]) i2 = m;
    const float e2 = expf(v[i2] - v[i1]);
    const float winv = 1.0f / (1.0f + e2);
    const float w1 = winv, w2 = e2 * winv;
    const float* p1 = mixedb + (((size_t)i1 * TOK + tok) << 9);
    const float* p2 = mixedb + (((size_t)i2 * TOK + tok) << 9);
    const int h0 = tid, h1 = tid + 256;
    const float c0 = w1 * p1[h0] + w2 * p2[h0];
    const float c1 = w1 * p1[h1] + w2 * p2[h1];
    float s = c0 + c1, sq = c0 * c0 + c1 * c1;
    #pragma unroll
    for (int off = 32; off; off >>= 1) {
        s += __shfl_xor(s, off, 64);
        sq += __shfl_xor(sq, off, 64);
    }
    __shared__ float red[8];
    const int wv = tid >> 6, ln = tid & 63;
    if (ln == 0) { red[wv] = s; red[4 + wv] = sq; }
    __syncthreads();
    s = red[0] + red[1] + red[2] + red[3];
    sq = red[4] + red[5] + red[6] + red[7];
    const float mu = s * (1.0f / 512.0f);
    const float var = sq * (1.0f / 512.0f) - mu * mu;
    const float r = 1.0f / sqrtf(var + 1e-5f);
    out[((size_t)tok << 9) + h0] = (c0 - mu) * r * g[h0] + bta[h0];
    out[((size_t)tok << 9) + h1] = (c1 - mu) * r * g[h1] + bta[h1];
}

extern "C" void kernel_launch(void* const* d_in, const int* in_sizes, int n_in,
                              void* d_out, int out_size, void* d_ws, size_t ws_size,
                              hipStream_t stream)
{
    (void)in_sizes; (void)n_in; (void)out_size; (void)ws_size;
    const float* ew1  = (const float*)d_in[12];
    const float* eb1  = (const float*)d_in[13];
    const float* ew2  = (const float*)d_in[14];
    const float* eb2  = (const float*)d_in[15];
    const float* rw1  = (const float*)d_in[16];
    const float* rb1  = (const float*)d_in[17];
    const float* rw2  = (const float*)d_in[18];
    const float* rb2  = (const float*)d_in[19];
    const float* sw1  = (const float*)d_in[20];
    const float* sb1  = (const float*)d_in[21];
    const float* sw2  = (const float*)d_in[22];
    const float* sb2  = (const float*)d_in[23];
    const float* ln_g = (const float*)d_in[24];
    const float* ln_b = (const float*)d_in[25];
    const int KD[4] = {1024, 64, 768, 512};

    // ---- workspace layout ----
    char* p = (char*)d_ws;
    auto alloc = [&](size_t bytes) {
        void* r = (void*)p;
        p += (bytes + 255) & ~(size_t)255;
        return r;
    };
    float*     mixedb  = (float*)alloc((size_t)4 * TOK * HD * 4);
    float*     scratch = (float*)alloc((size_t)TOK * HD * 4);   // t / u
    float*     route_w = (float*)alloc((size_t)TOK * 8 * 4);
    float*     mlog    = (float*)alloc((size_t)TOK * 4 * 4);
    _Float16*  xh      = (_Float16*)alloc((size_t)TOK * HD * 2);
    _Float16*  xl      = (_Float16*)alloc((size_t)TOK * HD * 2);
    _Float16*  mxh     = (_Float16*)alloc((size_t)TOK * HD * 2);
    _Float16*  mxl     = (_Float16*)alloc((size_t)TOK * HD * 2);
    _Float16*  fh      = (_Float16*)alloc((size_t)TOK * 1024 * 2);
    _Float16*  fl      = (_Float16*)alloc((size_t)TOK * 1024 * 2);
    _Float16*  pwh     = (_Float16*)alloc((size_t)1024 * HD * 2);
    _Float16*  pwl     = (_Float16*)alloc((size_t)1024 * HD * 2);
    _Float16*  rw1h    = (_Float16*)alloc((size_t)HD * HD * 2);
    _Float16*  rw1l    = (_Float16*)alloc((size_t)HD * HD * 2);
    _Float16*  sw1h    = (_Float16*)alloc((size_t)HD * HD * 2);
    _Float16*  sw1l    = (_Float16*)alloc((size_t)HD * HD * 2);
    _Float16*  w1h     = (_Float16*)alloc((size_t)8 * HD * HD * 2);
    _Float16*  w1l     = (_Float16*)alloc((size_t)8 * HD * HD * 2);
    _Float16*  w2h     = (_Float16*)alloc((size_t)8 * HD * HD * 2);
    _Float16*  w2l     = (_Float16*)alloc((size_t)8 * HD * HD * 2);

    // ---- weight prep (frag layout splits) ----
    split_w_kernel<<<dim3(1024), 256, 0, stream>>>(ew1, w1h, w1l);
    split_w_kernel<<<dim3(1024), 256, 0, stream>>>(ew2, w2h, w2l);
    split_w_kernel<<<dim3(128), 256, 0, stream>>>(rw1, rw1h, rw1l);
    split_w_kernel<<<dim3(128), 256, 0, stream>>>(sw1, sw1h, sw1l);

    for (int mod = 0; mod < 4; ++mod) {
        const float* feat = (const float*)d_in[mod * 3 + 0];
        const float* pw   = (const float*)d_in[mod * 3 + 1];
        const float* pb   = (const float*)d_in[mod * 3 + 2];
        float* mixm = mixedb + (size_t)mod * TOK * HD;
        const int K = KD[mod];

        // splits for this modality
        split_x_kernel<<<dim3(TOK * K / 2048), 256, 0, stream>>>(feat, fh, fl);
        split_w_kernel<<<dim3(K / 4), 256, 0, stream>>>(pw, pwh, pwl);
        // x = feat @ pw + pb  -> xh/xl directly
        gemm_hh<0, 1><<<dim3(4, 64), 256, 0, stream>>>(
            fh, fl, pwh, pwl, pb, K, nullptr, xh, xl);
        // t = gelu(x @ rw1 + rb1)
        gemm_hh<1, 0><<<dim3(4, 64), 256, 0, stream>>>(
            xh, xl, rw1h, rw1l, rb1, HD, scratch, nullptr, nullptr);
        // route_w = softmax(t @ rw2 + rb2)
        router_kernel<<<dim3(TOK / 4), 256, 0, stream>>>(scratch, rw2, rb2, route_w);
        // mixed = sum_e rw*eb2, then fused experts accumulate
        init_mixed<<<dim3(TOK * HD / 4 / 256), 256, 0, stream>>>(route_w, eb2, mixm);
        fused_expert2<<<dim3(1024), 256, 0, stream>>>(
            xh, xl, w1h, w1l, w2h, w2l, eb1, route_w, mixm);
        // u = gelu(mixed @ sw1 + sb1)
        split_x_kernel<<<dim3(TOK * HD / 2048), 256, 0, stream>>>(mixm, mxh, mxl);
        gemm_hh<1, 0><<<dim3(4, 64), 256, 0, stream>>>(
            mxh, mxl, sw1h, sw1l, sb1, HD, scratch, nullptr, nullptr);
        // mlog[:,mod]
        score_kernel<<<dim3(TOK / 4), 256, 0, stream>>>(scratch, sw2, sb2, mlog, mod);
    }
    final_kernel<<<dim3(TOK), 256, 0, stream>>>(mixedb, mlog, ln_g, ln_b, (float*)d_out);
}

// Round 6
// 1309.741 us; speedup vs baseline: 6.0791x; 6.0791x over previous
//
#include <hip/hip_runtime.h>
#include <math.h>

#define TOK 4096
#define HD 512

typedef _Float16 f16x8 __attribute__((ext_vector_type(8)));
typedef float f32x4 __attribute__((ext_vector_type(4)));

__device__ __forceinline__ float gelu_f(float x) {
    return 0.5f * x * (1.0f + erff(x * 0.70710678118654752f));
}

__device__ __forceinline__ void gload16(const void* g, void* l) {
    __builtin_amdgcn_global_load_lds((const __attribute__((address_space(1))) void*)g,
                                     (__attribute__((address_space(3))) void*)l, 16, 0, 0);
}

__device__ __forceinline__ void split2(float v, _Float16& h, _Float16& l) {
    h = (_Float16)v;
    l = (_Float16)(v - (float)h);
}

// ------------------------------------------------------------------
// fp32 -> (hi,lo) fp16, 8 elems/thread. grid = numel/2048
// ------------------------------------------------------------------
__global__ __launch_bounds__(256)
void split_x_kernel(const float* __restrict__ in, _Float16* __restrict__ hi,
                    _Float16* __restrict__ lo)
{
    const size_t idx = (size_t)blockIdx.x * 256 + threadIdx.x;
    const float4 v0 = *(const float4*)(in + idx * 8);
    const float4 v1 = *(const float4*)(in + idx * 8 + 4);
    float vv[8] = {v0.x, v0.y, v0.z, v0.w, v1.x, v1.y, v1.z, v1.w};
    f16x8 h, l;
    #pragma unroll
    for (int j = 0; j < 8; ++j) {
        _Float16 a, b; split2(vv[j], a, b);
        h[j] = a; l[j] = b;
    }
    *(f16x8*)(hi + idx * 8) = h;
    *(f16x8*)(lo + idx * 8) = l;
}

// ------------------------------------------------------------------
// Weight prep: [Ktot][512] fp32 row-major -> frag layout [Ktot/8][512][8]
// hi/lo fp16 (8 = k-minor). grid = Ktot*512/2048 blocks.
// ------------------------------------------------------------------
__global__ __launch_bounds__(256)
void split_w_kernel(const float* __restrict__ w, _Float16* __restrict__ hi,
                    _Float16* __restrict__ lo)
{
    const int idx = blockIdx.x * 256 + threadIdx.x;
    const int kbG = idx >> 9, n = idx & 511;
    const float* src = w + (((size_t)kbG * 8) << 9) + n;
    f16x8 h, l;
    #pragma unroll
    for (int j = 0; j < 8; ++j) {
        const float v = src[(size_t)j << 9];
        _Float16 a, b; split2(v, a, b);
        h[j] = a; l[j] = b;
    }
    *(f16x8*)(hi + (size_t)idx * 8) = h;
    *(f16x8*)(lo + (size_t)idx * 8) = l;
}

// ------------------------------------------------------------------
// Split-fp16 MFMA GEMM: out[M=4096][512] = act(A[M][K] @ Bfrag + bias)
// A row-major fp16 hi/lo; B frag layout [K/8][512][8] hi/lo.
// BM=64, BN=128, 4 waves (wave n-slice 32). grid (4, 64).
// OSPL: 0 = fp32 out; 1 = split fp16 out; 2 = score mode (no store,
//       atomicAdd sum(gelu(v)*sw2[n]) into mlog4[m*4]).
// ------------------------------------------------------------------
template<int ACT, int OSPL>
__global__ __launch_bounds__(256, 2)
void gemm_hh(const _Float16* __restrict__ ah, const _Float16* __restrict__ al,
             const _Float16* __restrict__ bh, const _Float16* __restrict__ bl,
             const float* __restrict__ bias, int K,
             float* __restrict__ outF,
             _Float16* __restrict__ oh, _Float16* __restrict__ ol,
             const float* __restrict__ sw2, float* __restrict__ mlog4)
{
    __shared__ _Float16 Ah[2][2048], Al[2][2048];
    const int tid = threadIdx.x;
    const int l = tid & 63, w = tid >> 6;
    const int kb = l >> 4, lr = l & 15;
    const int m0 = blockIdx.y << 6;
    const int wn0 = (blockIdx.x << 7) + (w << 5);
    const int scr = tid & 63, sckb = tid >> 6;
    const int sbase = (tid & 192) * 8;

    f32x4 acc[4][2];
    #pragma unroll
    for (int i = 0; i < 4; ++i)
        #pragma unroll
        for (int j = 0; j < 2; ++j) acc[i][j] = (f32x4){0.f, 0.f, 0.f, 0.f};

    {
        const size_t ga = (size_t)(m0 + scr) * K + sckb * 8;
        gload16(ah + ga, Ah[0] + sbase);
        gload16(al + ga, Al[0] + sbase);
    }
    int cur = 0;
    for (int k0 = 0; k0 < K; k0 += 32) {
        __syncthreads();
        if (k0 + 32 < K) {
            const size_t ga = (size_t)(m0 + scr) * K + k0 + 32 + sckb * 8;
            gload16(ah + ga, Ah[cur ^ 1] + sbase);
            gload16(al + ga, Al[cur ^ 1] + sbase);
        }
        f16x8 fah[4], fal[4];
        #pragma unroll
        for (int i = 0; i < 4; ++i) {
            const int off = (kb * 64 + i * 16 + lr) * 8;
            fah[i] = *(const f16x8*)(Ah[cur] + off);
            fal[i] = *(const f16x8*)(Al[cur] + off);
        }
        #pragma unroll
        for (int j = 0; j < 2; ++j) {
            const size_t gb = ((size_t)(((k0 >> 3) + kb) << 9) + wn0 + j * 16 + lr) * 8;
            const f16x8 fbh = *(const f16x8*)(bh + gb);
            const f16x8 fbl = *(const f16x8*)(bl + gb);
            #pragma unroll
            for (int i = 0; i < 4; ++i) {
                acc[i][j] = __builtin_amdgcn_mfma_f32_16x16x32_f16(fah[i], fbh, acc[i][j], 0, 0, 0);
                acc[i][j] = __builtin_amdgcn_mfma_f32_16x16x32_f16(fah[i], fbl, acc[i][j], 0, 0, 0);
                acc[i][j] = __builtin_amdgcn_mfma_f32_16x16x32_f16(fal[i], fbh, acc[i][j], 0, 0, 0);
            }
        }
        cur ^= 1;
    }
    #pragma unroll
    for (int i = 0; i < 4; ++i) {
        float sacc[4] = {0.f, 0.f, 0.f, 0.f};   // score partials per r
        #pragma unroll
        for (int j = 0; j < 2; ++j) {
            const int n = wn0 + j * 16 + lr;
            const float bv = bias[n];
            const float swv = (OSPL == 2) ? sw2[n] : 0.f;
            #pragma unroll
            for (int r = 0; r < 4; ++r) {
                const int m = m0 + i * 16 + (kb << 2) + r;
                float v = acc[i][j][r] + bv;
                if (ACT) v = gelu_f(v);
                if (OSPL == 2) {
                    sacc[r] = fmaf(v, swv, sacc[r]);
                } else if (OSPL == 1) {
                    _Float16 vh, vl; split2(v, vh, vl);
                    oh[((size_t)m << 9) + n] = vh;
                    ol[((size_t)m << 9) + n] = vl;
                } else {
                    outF[((size_t)m << 9) + n] = v;
                }
            }
        }
        if (OSPL == 2) {
            #pragma unroll
            for (int r = 0; r < 4; ++r) {
                float s = sacc[r];
                s += __shfl_xor(s, 1, 64);
                s += __shfl_xor(s, 2, 64);
                s += __shfl_xor(s, 4, 64);
                s += __shfl_xor(s, 8, 64);
                if (lr == 0) {
                    const int m = m0 + i * 16 + (kb << 2) + r;
                    atomicAdd(&mlog4[m << 2], s);
                }
            }
        }
    }
}

// ------------------------------------------------------------------
// Fused expert, 512 threads. One (64-token tile, expert) per block.
// grid = (64, 8)  [y = expert: expert-major dispatch keeps each expert's
// 2 MB weight set L2-hot -- R5 showed interleaving experts thrashes L2].
// Stage 1: H = gelu(X@W1e + b1e)*rw -> LDS split-fp16, subtiled
//          [kgroup][row][8] (conflict-free b128 reads).
// Stage 2: mixed += H @ W2e (atomicAdd; bias via init_mixed).
// LDS: H 131072 B + X dbuf 16384 B = 147456 B -> 1 block/CU, 8 waves.
// ------------------------------------------------------------------
__global__ __launch_bounds__(512, 1)
void fused_expert3(const _Float16* __restrict__ xh, const _Float16* __restrict__ xl,
                   const _Float16* __restrict__ w1h, const _Float16* __restrict__ w1l,
                   const _Float16* __restrict__ w2h, const _Float16* __restrict__ w2l,
                   const float* __restrict__ eb1, const float* __restrict__ rw,
                   float* __restrict__ mixed)
{
    __shared__ _Float16 Hh[32768], Hl[32768];     // [64 kgrp][64 row][8]
    __shared__ _Float16 Xh[2][2048], Xl[2][2048]; // [4 kgrp][64 row][8]
    const int tid = threadIdx.x;
    const int w = tid >> 6, l = tid & 63;
    const int kb = l >> 4, lr = l & 15;
    const int e = blockIdx.y;
    const int m0 = blockIdx.x << 6;
    const int wm = w >> 2, wn = w & 3;            // 2 x 4 wave grid
    const int sw = w & 3;                         // staging k-group
    const int sbase = sw << 9;                    // wave-uniform, halfs

    const _Float16* w1he = w1h + ((size_t)e << 18);
    const _Float16* w1le = w1l + ((size_t)e << 18);
    const _Float16* w2he = w2h + ((size_t)e << 18);
    const _Float16* w2le = w2l + ((size_t)e << 18);

    f32x4 acc1[2][8];
    #pragma unroll
    for (int i = 0; i < 2; ++i)
        #pragma unroll
        for (int j = 0; j < 8; ++j) acc1[i][j] = (f32x4){0.f, 0.f, 0.f, 0.f};

    // ---- stage 1: acc1 = X @ W1e ----
    {
        const size_t ga = ((size_t)(m0 + l) << 9) + (sw << 3);
        if (tid < 256) gload16(xh + ga, Xh[0] + sbase);
        else           gload16(xl + ga, Xl[0] + sbase);
    }
    int cur = 0;
    for (int k0 = 0; k0 < 512; k0 += 32) {
        __syncthreads();
        if (k0 + 32 < 512) {
            const size_t ga = ((size_t)(m0 + l) << 9) + k0 + 32 + (sw << 3);
            if (tid < 256) gload16(xh + ga, Xh[cur ^ 1] + sbase);
            else           gload16(xl + ga, Xl[cur ^ 1] + sbase);
        }
        f16x8 fah[2], fal[2];
        #pragma unroll
        for (int i = 0; i < 2; ++i) {
            const int off = (kb * 64 + wm * 32 + i * 16 + lr) * 8;
            fah[i] = *(const f16x8*)(Xh[cur] + off);
            fal[i] = *(const f16x8*)(Xl[cur] + off);
        }
        #pragma unroll
        for (int j = 0; j < 8; ++j) {
            const int n = wn * 128 + j * 16 + lr;
            const size_t gb = ((size_t)(((k0 >> 3) + kb) << 9) + n) * 8;
            const f16x8 fbh = *(const f16x8*)(w1he + gb);
            const f16x8 fbl = *(const f16x8*)(w1le + gb);
            #pragma unroll
            for (int i = 0; i < 2; ++i) {
                acc1[i][j] = __builtin_amdgcn_mfma_f32_16x16x32_f16(fah[i], fbh, acc1[i][j], 0, 0, 0);
                acc1[i][j] = __builtin_amdgcn_mfma_f32_16x16x32_f16(fah[i], fbl, acc1[i][j], 0, 0, 0);
                acc1[i][j] = __builtin_amdgcn_mfma_f32_16x16x32_f16(fal[i], fbh, acc1[i][j], 0, 0, 0);
            }
        }
        cur ^= 1;
    }
    // ---- epilogue 1: gelu+bias+route-scale -> H (split fp16, subtiled) ----
    __syncthreads();
    #pragma unroll
    for (int i = 0; i < 2; ++i)
        #pragma unroll
        for (int j = 0; j < 8; ++j) {
            const int n = wn * 128 + j * 16 + lr;
            const float bv = eb1[(e << 9) + n];
            #pragma unroll
            for (int r = 0; r < 4; ++r) {
                const int ri = wm * 32 + i * 16 + (kb << 2) + r;
                const float v = gelu_f(acc1[i][j][r] + bv) * rw[((size_t)(m0 + ri) << 3) + e];
                _Float16 vh, vl; split2(v, vh, vl);
                const int off = ((n >> 3) * 64 + ri) * 8 + (n & 7);
                Hh[off] = vh; Hl[off] = vl;
            }
        }
    __syncthreads();

    // ---- stage 2: acc2 = H @ W2e ----
    f32x4 acc2[2][8];
    #pragma unroll
    for (int i = 0; i < 2; ++i)
        #pragma unroll
        for (int j = 0; j < 8; ++j) acc2[i][j] = (f32x4){0.f, 0.f, 0.f, 0.f};

    for (int k0 = 0; k0 < 512; k0 += 32) {
        f16x8 fah[2], fal[2];
        #pragma unroll
        for (int i = 0; i < 2; ++i) {
            const int off = (((k0 >> 3) + kb) * 64 + wm * 32 + i * 16 + lr) * 8;
            fah[i] = *(const f16x8*)(Hh + off);
            fal[i] = *(const f16x8*)(Hl + off);
        }
        #pragma unroll
        for (int j = 0; j < 8; ++j) {
            const int n = wn * 128 + j * 16 + lr;
            const size_t gb = ((size_t)(((k0 >> 3) + kb) << 9) + n) * 8;
            const f16x8 fbh = *(const f16x8*)(w2he + gb);
            const f16x8 fbl = *(const f16x8*)(w2le + gb);
            #pragma unroll
            for (int i = 0; i < 2; ++i) {
                acc2[i][j] = __builtin_amdgcn_mfma_f32_16x16x32_f16(fah[i], fbh, acc2[i][j], 0, 0, 0);
                acc2[i][j] = __builtin_amdgcn_mfma_f32_16x16x32_f16(fah[i], fbl, acc2[i][j], 0, 0, 0);
                acc2[i][j] = __builtin_amdgcn_mfma_f32_16x16x32_f16(fal[i], fbh, acc2[i][j], 0, 0, 0);
            }
        }
    }
    #pragma unroll
    for (int i = 0; i < 2; ++i)
        #pragma unroll
        for (int j = 0; j < 8; ++j) {
            const int n = wn * 128 + j * 16 + lr;
            #pragma unroll
            for (int r = 0; r < 4; ++r) {
                const int m = m0 + wm * 32 + i * 16 + (kb << 2) + r;
                atomicAdd(&mixed[((size_t)m << 9) + n], acc2[i][j][r]);
            }
        }
}

// ------------------------------------------------------------------
// mixed init: mixed[m][n] = sum_e rw[m][e] * eb2[e][n]. grid = 2048
// ------------------------------------------------------------------
__global__ __launch_bounds__(256)
void init_mixed(const float* __restrict__ rw, const float* __restrict__ eb2,
                float* __restrict__ mixed)
{
    const int idx = blockIdx.x * 256 + threadIdx.x;
    const int m = idx >> 7, n4 = (idx & 127) << 2;
    float rwv[8];
    #pragma unroll
    for (int e = 0; e < 8; ++e) rwv[e] = rw[(m << 3) + e];
    float4 o = {0.f, 0.f, 0.f, 0.f};
    #pragma unroll
    for (int e = 0; e < 8; ++e) {
        const float4 b = *(const float4*)(eb2 + (e << 9) + n4);
        o.x = fmaf(rwv[e], b.x, o.x); o.y = fmaf(rwv[e], b.y, o.y);
        o.z = fmaf(rwv[e], b.z, o.z); o.w = fmaf(rwv[e], b.w, o.w);
    }
    *(float4*)(mixed + ((size_t)m << 9) + n4) = o;
}

// ------------------------------------------------------------------
// Router softmax
// ------------------------------------------------------------------
__global__ __launch_bounds__(256)
void router_kernel(const float* __restrict__ t,
                   const float* __restrict__ rw2,
                   const float* __restrict__ rb2,
                   float* __restrict__ route_w)
{
    __shared__ float s[512 * 9];
    const int tid = threadIdx.x;
    for (int idx = tid; idx < 4096; idx += 256)
        s[(idx >> 3) * 9 + (idx & 7)] = rw2[idx];
    __syncthreads();
    const int lane = tid & 63;
    const int tok = (blockIdx.x << 2) + (tid >> 6);
    const float* tp = t + ((size_t)tok << 9);
    float acc[8] = {};
    #pragma unroll
    for (int kq = 0; kq < 8; ++kq) {
        const int k = (kq << 6) + lane;
        const float tv = tp[k];
        #pragma unroll
        for (int e = 0; e < 8; ++e)
            acc[e] = fmaf(tv, s[k * 9 + e], acc[e]);
    }
    #pragma unroll
    for (int e = 0; e < 8; ++e)
        #pragma unroll
        for (int off = 32; off; off >>= 1)
            acc[e] += __shfl_xor(acc[e], off, 64);
    float mx = -1e30f;
    #pragma unroll
    for (int e = 0; e < 8; ++e) { acc[e] += rb2[e]; mx = fmaxf(mx, acc[e]); }
    float sum = 0.f;
    #pragma unroll
    for (int e = 0; e < 8; ++e) { acc[e] = expf(acc[e] - mx); sum += acc[e]; }
    const float inv = 1.0f / sum;
    if (lane == 0) {
        #pragma unroll
        for (int e = 0; e < 8; ++e) route_w[(tok << 3) + e] = acc[e] * inv;
    }
}

// ------------------------------------------------------------------
// Final: top-2 + masked softmax + blend + LayerNorm, one block/token.
// ------------------------------------------------------------------
__global__ __launch_bounds__(256)
void final_kernel(const float* __restrict__ mixedb,
                  const float* __restrict__ mlog,
                  const float* __restrict__ sb2,
                  const float* __restrict__ g,
                  const float* __restrict__ bta,
                  float* __restrict__ out)
{
    const int tok = blockIdx.x, tid = threadIdx.x;
    float v[4];
    #pragma unroll
    for (int m = 0; m < 4; ++m) v[m] = mlog[(tok << 2) + m] + sb2[0];
    int i1 = 0;
    #pragma unroll
    for (int m = 1; m < 4; ++m) if (v[m] > v[i1]) i1 = m;
    int i2 = (i1 == 0) ? 1 : 0;
    for (int m = i2 + 1; m < 4; ++m) if (m != i1 && v[m] > v[i2]) i2 = m;
    const float e2 = expf(v[i2] - v[i1]);
    const float winv = 1.0f / (1.0f + e2);
    const float w1 = winv, w2 = e2 * winv;
    const float* p1 = mixedb + (((size_t)i1 * TOK + tok) << 9);
    const float* p2 = mixedb + (((size_t)i2 * TOK + tok) << 9);
    const int h0 = tid, h1 = tid + 256;
    const float c0 = w1 * p1[h0] + w2 * p2[h0];
    const float c1 = w1 * p1[h1] + w2 * p2[h1];
    float s = c0 + c1, sq = c0 * c0 + c1 * c1;
    #pragma unroll
    for (int off = 32; off; off >>= 1) {
        s += __shfl_xor(s, off, 64);
        sq += __shfl_xor(sq, off, 64);
    }
    __shared__ float red[8];
    const int wv = tid >> 6, ln = tid & 63;
    if (ln == 0) { red[wv] = s; red[4 + wv] = sq; }
    __syncthreads();
    s = red[0] + red[1] + red[2] + red[3];
    sq = red[4] + red[5] + red[6] + red[7];
    const float mu = s * (1.0f / 512.0f);
    const float var = sq * (1.0f / 512.0f) - mu * mu;
    const float r = 1.0f / sqrtf(var + 1e-5f);
    out[((size_t)tok << 9) + h0] = (c0 - mu) * r * g[h0] + bta[h0];
    out[((size_t)tok << 9) + h1] = (c1 - mu) * r * g[h1] + bta[h1];
}

extern "C" void kernel_launch(void* const* d_in, const int* in_sizes, int n_in,
                              void* d_out, int out_size, void* d_ws, size_t ws_size,
                              hipStream_t stream)
{
    (void)in_sizes; (void)n_in; (void)out_size; (void)ws_size;
    const float* ew1  = (const float*)d_in[12];
    const float* eb1  = (const float*)d_in[13];
    const float* ew2  = (const float*)d_in[14];
    const float* eb2  = (const float*)d_in[15];
    const float* rw1  = (const float*)d_in[16];
    const float* rb1  = (const float*)d_in[17];
    const float* rw2  = (const float*)d_in[18];
    const float* rb2  = (const float*)d_in[19];
    const float* sw1  = (const float*)d_in[20];
    const float* sb1  = (const float*)d_in[21];
    const float* sw2  = (const float*)d_in[22];
    const float* sb2  = (const float*)d_in[23];
    const float* ln_g = (const float*)d_in[24];
    const float* ln_b = (const float*)d_in[25];
    const int KD[4] = {1024, 64, 768, 512};

    // ---- workspace layout ----
    char* p = (char*)d_ws;
    auto alloc = [&](size_t bytes) {
        void* r = (void*)p;
        p += (bytes + 255) & ~(size_t)255;
        return r;
    };
    float*     mixedb  = (float*)alloc((size_t)4 * TOK * HD * 4);
    float*     scratch = (float*)alloc((size_t)TOK * HD * 4);   // t
    float*     route_w = (float*)alloc((size_t)TOK * 8 * 4);
    float*     mlog    = (float*)alloc((size_t)TOK * 4 * 4);
    _Float16*  xh      = (_Float16*)alloc((size_t)TOK * HD * 2);
    _Float16*  xl      = (_Float16*)alloc((size_t)TOK * HD * 2);
    _Float16*  mxh     = (_Float16*)alloc((size_t)TOK * HD * 2);
    _Float16*  mxl     = (_Float16*)alloc((size_t)TOK * HD * 2);
    _Float16*  fh      = (_Float16*)alloc((size_t)TOK * 1024 * 2);
    _Float16*  fl      = (_Float16*)alloc((size_t)TOK * 1024 * 2);
    _Float16*  pwh     = (_Float16*)alloc((size_t)1024 * HD * 2);
    _Float16*  pwl     = (_Float16*)alloc((size_t)1024 * HD * 2);
    _Float16*  rw1h    = (_Float16*)alloc((size_t)HD * HD * 2);
    _Float16*  rw1l    = (_Float16*)alloc((size_t)HD * HD * 2);
    _Float16*  sw1h    = (_Float16*)alloc((size_t)HD * HD * 2);
    _Float16*  sw1l    = (_Float16*)alloc((size_t)HD * HD * 2);
    _Float16*  w1h     = (_Float16*)alloc((size_t)8 * HD * HD * 2);
    _Float16*  w1l     = (_Float16*)alloc((size_t)8 * HD * HD * 2);
    _Float16*  w2h     = (_Float16*)alloc((size_t)8 * HD * HD * 2);
    _Float16*  w2l     = (_Float16*)alloc((size_t)8 * HD * HD * 2);

    // mlog accumulated via atomics -> zero it (ws is re-poisoned every call)
    hipMemsetAsync(mlog, 0, (size_t)TOK * 4 * sizeof(float), stream);

    // ---- weight prep (frag layout splits) ----
    split_w_kernel<<<dim3(1024), 256, 0, stream>>>(ew1, w1h, w1l);
    split_w_kernel<<<dim3(1024), 256, 0, stream>>>(ew2, w2h, w2l);
    split_w_kernel<<<dim3(128), 256, 0, stream>>>(rw1, rw1h, rw1l);
    split_w_kernel<<<dim3(128), 256, 0, stream>>>(sw1, sw1h, sw1l);

    for (int mod = 0; mod < 4; ++mod) {
        const float* feat = (const float*)d_in[mod * 3 + 0];
        const float* pw   = (const float*)d_in[mod * 3 + 1];
        const float* pb   = (const float*)d_in[mod * 3 + 2];
        float* mixm = mixedb + (size_t)mod * TOK * HD;
        const int K = KD[mod];

        // splits for this modality
        split_x_kernel<<<dim3(TOK * K / 2048), 256, 0, stream>>>(feat, fh, fl);
        split_w_kernel<<<dim3(K / 4), 256, 0, stream>>>(pw, pwh, pwl);
        // x = feat @ pw + pb  -> xh/xl
        gemm_hh<0, 1><<<dim3(4, 64), 256, 0, stream>>>(
            fh, fl, pwh, pwl, pb, K, nullptr, xh, xl, nullptr, nullptr);
        // t = gelu(x @ rw1 + rb1)
        gemm_hh<1, 0><<<dim3(4, 64), 256, 0, stream>>>(
            xh, xl, rw1h, rw1l, rb1, HD, scratch, nullptr, nullptr, nullptr, nullptr);
        // route_w = softmax(t @ rw2 + rb2)
        router_kernel<<<dim3(TOK / 4), 256, 0, stream>>>(scratch, rw2, rb2, route_w);
        // mixed = sum_e rw*eb2, then fused experts accumulate
        init_mixed<<<dim3(TOK * HD / 4 / 256), 256, 0, stream>>>(route_w, eb2, mixm);
        fused_expert3<<<dim3(64, 8), 512, 0, stream>>>(
            xh, xl, w1h, w1l, w2h, w2l, eb1, route_w, mixm);
        // u = gelu(mixed @ sw1 + sb1); score fused into epilogue -> mlog
        split_x_kernel<<<dim3(TOK * HD / 2048), 256, 0, stream>>>(mixm, mxh, mxl);
        gemm_hh<1, 2><<<dim3(4, 64), 256, 0, stream>>>(
            mxh, mxl, sw1h, sw1l, sb1, HD, nullptr, nullptr, nullptr,
            sw2, mlog + mod);
        // note: mlog4 indexed as mlog[m*4 + mod] via base offset
    }
    final_kernel<<<dim3(TOK), 256, 0, stream>>>(mixedb, mlog, sb2, ln_g, ln_b, (float*)d_out);
}